// Round 7
// baseline (145.016 us; speedup 1.0000x reference)
//
#include <hip/hip_runtime.h>

#define NN 100000
#define NE 1600000

constexpr int F_IN = 58;
constexpr int F_H  = 16;
constexpr int KS   = 2;
constexpr int FH2  = 32;            // KS * F_H
constexpr int NODES_PER_BLK = 8;
constexpr int SXP = 60;             // padded x-row stride (even, for float2 reads)
constexpr int NPAIR = F_IN / 2;     // 29

constexpr int NB   = 391;           // buckets: col >> 8
constexpr int NBLK = 256;           // partition blocks
constexpr int EPB  = NE / NBLK;     // 6250
constexpr int SCANN = NB * NBLK;    // 100096
constexpr int SCAN_BLOCKS = (SCANN + 1023) / 1024;  // 98
constexpr int DENSE_BLOCKS = (NN + NODES_PER_BLK - 1) / NODES_PER_BLK;

// blocks [0,NBLK): per-block bucket histogram (4-way replicated LDS atomics).
// blocks [NBLK,...): dense layer-1 with b128 weight reads.
__global__ void k_hist_dense1(const int* __restrict__ col, int* __restrict__ bh,
                              const float* __restrict__ x,
                              const float* __restrict__ Wi, const float* __restrict__ Wr,
                              const float* __restrict__ b,
                              float* __restrict__ h1, float* __restrict__ r1) {
    __shared__ float swq[NPAIR * 128];          // [pair][ko*4 + {wi_i,wr_i,wi_i1,wr_i1}]
    __shared__ float sx[NODES_PER_BLK * SXP];
    __shared__ int hist[4 * NB];
    int tid = threadIdx.x;

    if (blockIdx.x < NBLK) {
        int blk = blockIdx.x;
        for (int i = tid; i < 4 * NB; i += 256) hist[i] = 0;
        __syncthreads();
        int base = blk * EPB;
        int c0 = (tid & 3) * NB;
        for (int e = base + tid; e < base + EPB; e += 256)
            atomicAdd(&hist[c0 + (col[e] >> 8)], 1);
        __syncthreads();
        for (int i = tid; i < NB; i += 256)
            bh[i * NBLK + blk] = hist[i] + hist[NB + i] + hist[2 * NB + i] + hist[3 * NB + i];
        return;
    }

    // pack weights: pair p, lane ko -> {Wi[2p], Wr[2p], Wi[2p+1], Wr[2p+1]}
    for (int t = tid; t < NPAIR * 128; t += 256) {
        int p = t >> 7, r = t & 127;
        int ko = r >> 2, q = r & 3;
        int i = p * 2 + (q >> 1);
        int k = ko >> 4, o = ko & 15;
        const float* W = (q & 1) ? Wr : Wi;
        swq[t] = W[(k * F_IN + i) * F_H + o];
    }
    int nodeBase = (blockIdx.x - NBLK) * NODES_PER_BLK;
    for (int t = tid; t < NODES_PER_BLK * F_IN; t += 256) {
        int ln = t / F_IN, i = t - ln * F_IN;
        int n = nodeBase + ln;
        sx[ln * SXP + i] = (n < NN) ? x[n * F_IN + i] : 0.f;
    }
    __syncthreads();
    int ln = tid >> 5, ko = tid & 31;
    int n = nodeBase + ln;
    if (n >= NN) return;
    float hi = 0.f, hr = 0.f;
#pragma unroll
    for (int p = 0; p < NPAIR; p++) {
        float2 xv = *(const float2*)&sx[ln * SXP + p * 2];
        float4 wq = *(const float4*)&swq[(p << 7) + (ko << 2)];
        hi = fmaf(xv.x, wq.x, hi);
        hr = fmaf(xv.x, wq.y, hr);
        hi = fmaf(xv.y, wq.z, hi);
        hr = fmaf(xv.y, wq.w, hr);
    }
    h1[n * FH2 + ko] = hi;
    r1[n * FH2 + ko] = hr + b[ko];
}

__global__ void k_scan1(int* __restrict__ bh, int* __restrict__ bsum) {
    __shared__ int ts[256];
    int tid = threadIdx.x;
    int base = blockIdx.x * 1024 + tid * 4;
    int v0 = (base + 0 < SCANN) ? bh[base + 0] : 0;
    int v1 = (base + 1 < SCANN) ? bh[base + 1] : 0;
    int v2 = (base + 2 < SCANN) ? bh[base + 2] : 0;
    int v3 = (base + 3 < SCANN) ? bh[base + 3] : 0;
    int p0 = v0, p1 = p0 + v1, p2 = p1 + v2, p3 = p2 + v3;
    ts[tid] = p3;
    __syncthreads();
    for (int off = 1; off < 256; off <<= 1) {
        int v = (tid >= off) ? ts[tid - off] : 0;
        __syncthreads();
        ts[tid] += v;
        __syncthreads();
    }
    int prev = (tid > 0) ? ts[tid - 1] : 0;
    if (base + 0 < SCANN) bh[base + 0] = prev + p0;
    if (base + 1 < SCANN) bh[base + 1] = prev + p1;
    if (base + 2 < SCANN) bh[base + 2] = prev + p2;
    if (base + 3 < SCANN) bh[base + 3] = prev + p3;
    if (tid == 255) bsum[blockIdx.x] = ts[255];
}

__global__ void k_scan2(const int* __restrict__ bsum, int* __restrict__ boff) {
    __shared__ int s[128];
    int tid = threadIdx.x;
    s[tid] = (tid < SCAN_BLOCKS) ? bsum[tid] : 0;
    __syncthreads();
    for (int off = 1; off < 128; off <<= 1) {
        int v = (tid >= off) ? s[tid - off] : 0;
        __syncthreads();
        s[tid] += v;
        __syncthreads();
    }
    if (tid < SCAN_BLOCKS) boff[tid] = (tid > 0) ? s[tid - 1] : 0;
}

__global__ void k_scan3(int* __restrict__ bh, const int* __restrict__ boff) {
    int i = blockIdx.x * blockDim.x + threadIdx.x;
    if (i < SCANN) bh[i] += boff[i >> 10];
}

__global__ void k_bscatter(const int* __restrict__ row, const int* __restrict__ col,
                           const int* __restrict__ bh, int* __restrict__ ebuck) {
    __shared__ int cur[NB];
    int tid = threadIdx.x, blk = blockIdx.x;
    for (int i = tid; i < NB; i += 256) {
        int idx = i * NBLK + blk;
        cur[i] = (idx == 0) ? 0 : bh[idx - 1];
    }
    __syncthreads();
    int base = blk * EPB;
    for (int e = base + tid; e < base + EPB; e += 256) {
        int c = col[e];
        int pos = atomicAdd(&cur[c >> 8], 1);
        ebuck[pos] = (row[e] << 8) | (c & 255);
    }
}

// per bucket: per-col counts (2-way replicated) + scan -> inc, dis
__global__ void __launch_bounds__(256) k_bcsr_a(const int* __restrict__ bh,
                                                const int* __restrict__ ebuck,
                                                int* __restrict__ inc, float* __restrict__ dis) {
    __shared__ int cnt[514];
    __shared__ int scn[256];
    int b = blockIdx.x, tid = threadIdx.x;
    int start = (b == 0) ? 0 : bh[b * NBLK - 1];
    int end   = bh[(b + 1) * NBLK - 1];
    cnt[tid] = 0; cnt[257 + tid] = 0;
    __syncthreads();
    int c0 = (tid & 1) * 257;
    for (int j = start + tid; j < end; j += 256)
        atomicAdd(&cnt[c0 + (ebuck[j] & 255)], 1);
    __syncthreads();
    int v = cnt[tid] + cnt[257 + tid];
    scn[tid] = v;
    __syncthreads();
    for (int off = 1; off < 256; off <<= 1) {
        int t = (tid >= off) ? scn[tid - off] : 0;
        __syncthreads();
        scn[tid] += t;
        __syncthreads();
    }
    int colIdx = (b << 8) + tid;
    if (colIdx < NN) {
        inc[colIdx] = start + scn[tid];
        dis[colIdx] = (v > 0) ? rsqrtf((float)v) : 0.f;
    }
}

// per bucket: scatter packed (src, w = dis[src]*dis[col]) into CSR order
__global__ void __launch_bounds__(256) k_bcsr_b(const int* __restrict__ bh,
                                                const int* __restrict__ ebuck,
                                                const int* __restrict__ inc,
                                                const float* __restrict__ dis,
                                                int2* __restrict__ esrc8) {
    __shared__ int cur[256];
    __shared__ float sdis[256];
    int b = blockIdx.x, tid = threadIdx.x;
    int start = (b == 0) ? 0 : bh[b * NBLK - 1];
    int end   = bh[(b + 1) * NBLK - 1];
    int colIdx = (b << 8) + tid;
    cur[tid]  = (colIdx == 0) ? 0 : ((colIdx <= NN) ? inc[colIdx - 1] : 0);
    sdis[tid] = (colIdx < NN) ? dis[colIdx] : 0.f;
    __syncthreads();
    for (int j = start + tid; j < end; j += 256) {
        int e = ebuck[j];
        int c = e & 255, s = e >> 8;
        int pos = atomicAdd(&cur[c], 1);
        float w = dis[s] * sdis[c];
        esrc8[pos] = make_int2(s, __float_as_int(w));
    }
}

// layer1 gather + relu + K-mean + dense2. 8 lanes/node, float4 rows, packed edges.
__global__ void k_gather1_mid(const int* __restrict__ inc, const int2* __restrict__ esrc8,
                              const float4* __restrict__ h1, const float4* __restrict__ r1,
                              const float4* __restrict__ Wi2, const float4* __restrict__ Wr2,
                              const float* __restrict__ b2,
                              float* __restrict__ h2, float* __restrict__ r2) {
    int tid = blockIdx.x * blockDim.x + threadIdx.x;
    int n = tid >> 3, l = tid & 7;
    if (n >= NN) return;
    int js = (n == 0) ? 0 : inc[n - 1];
    int je = inc[n];
    float4 acc = r1[(size_t)n * 8 + l];
    int j = js;
    if ((j & 1) && j < je) {                     // align to pair
        int2 e = esrc8[j];
        float w = __int_as_float(e.y);
        float4 v = h1[(size_t)e.x * 8 + l];
        acc.x = fmaf(w, v.x, acc.x); acc.y = fmaf(w, v.y, acc.y);
        acc.z = fmaf(w, v.z, acc.z); acc.w = fmaf(w, v.w, acc.w);
        j++;
    }
    for (; j + 1 < je; j += 2) {
        int4 ep = *(const int4*)&esrc8[j];       // 2 edges, one b128
        float w0 = __int_as_float(ep.y), w1 = __int_as_float(ep.w);
        float4 v0 = h1[(size_t)ep.x * 8 + l];
        float4 v1 = h1[(size_t)ep.z * 8 + l];
        acc.x = fmaf(w0, v0.x, acc.x); acc.y = fmaf(w0, v0.y, acc.y);
        acc.z = fmaf(w0, v0.z, acc.z); acc.w = fmaf(w0, v0.w, acc.w);
        acc.x = fmaf(w1, v1.x, acc.x); acc.y = fmaf(w1, v1.y, acc.y);
        acc.z = fmaf(w1, v1.z, acc.z); acc.w = fmaf(w1, v1.w, acc.w);
    }
    if (j < je) {
        int2 e = esrc8[j];
        float w = __int_as_float(e.y);
        float4 v = h1[(size_t)e.x * 8 + l];
        acc.x = fmaf(w, v.x, acc.x); acc.y = fmaf(w, v.y, acc.y);
        acc.z = fmaf(w, v.z, acc.z); acc.w = fmaf(w, v.w, acc.w);
    }
    acc.x = fmaxf(acc.x, 0.f); acc.y = fmaxf(acc.y, 0.f);
    acc.z = fmaxf(acc.z, 0.f); acc.w = fmaxf(acc.w, 0.f);
    float4 h;
    h.x = 0.5f * (acc.x + __shfl_xor(acc.x, 4));
    h.y = 0.5f * (acc.y + __shfl_xor(acc.y, 4));
    h.z = 0.5f * (acc.z + __shfl_xor(acc.z, 4));
    h.w = 0.5f * (acc.w + __shfl_xor(acc.w, 4));
    float4 wi = Wi2[l], wr = Wr2[l];
    float p1 = h.x * wi.x + h.y * wi.y + h.z * wi.z + h.w * wi.w;
    float p2 = h.x * wr.x + h.y * wr.y + h.z * wr.z + h.w * wr.w;
    p1 += __shfl_xor(p1, 1); p1 += __shfl_xor(p1, 2);
    p2 += __shfl_xor(p2, 1); p2 += __shfl_xor(p2, 2);
    if ((l & 3) == 0) {
        int k = l >> 2;
        h2[n * 2 + k] = p1;
        r2[n * 2 + k] = p2 + b2[k];
    }
}

// layer2 gather: 8 lanes/node, edge-parallel over packed pairs
__global__ void k_gather2(const int* __restrict__ inc, const int2* __restrict__ esrc8,
                          const float* __restrict__ h2, const float* __restrict__ r2,
                          float* __restrict__ out) {
    int tid = blockIdx.x * blockDim.x + threadIdx.x;
    int n = tid >> 3, l = tid & 7;
    if (n >= NN) return;
    int js = (n == 0) ? 0 : inc[n - 1];
    int je = inc[n];
    float a0 = 0.f, a1v = 0.f;
    for (int j = js + l; j < je; j += 8) {
        int2 e = esrc8[j];
        float w = __int_as_float(e.y);
        float2 hv = *(const float2*)&h2[(size_t)e.x * 2];
        a0  = fmaf(w, hv.x, a0);
        a1v = fmaf(w, hv.y, a1v);
    }
    a0  += __shfl_xor(a0, 1);  a0  += __shfl_xor(a0, 2);  a0  += __shfl_xor(a0, 4);
    a1v += __shfl_xor(a1v, 1); a1v += __shfl_xor(a1v, 2); a1v += __shfl_xor(a1v, 4);
    if (l == 0) {
        float2 rv = *(const float2*)&r2[(size_t)n * 2];
        out[n] = 0.5f * (fmaxf(a0 + rv.x, 0.f) + fmaxf(a1v + rv.y, 0.f));
    }
}

extern "C" void kernel_launch(void* const* d_in, const int* in_sizes, int n_in,
                              void* d_out, int out_size, void* d_ws, size_t ws_size,
                              hipStream_t stream) {
    const float* x   = (const float*)d_in[0];
    const int*   ei  = (const int*)d_in[1];
    const float* Wi1 = (const float*)d_in[2];
    const float* Wr1 = (const float*)d_in[3];
    const float* b1  = (const float*)d_in[4];
    const float* Wi2 = (const float*)d_in[5];
    const float* Wr2 = (const float*)d_in[6];
    const float* b2  = (const float*)d_in[7];
    float* out = (float*)d_out;

    const int* row = ei;
    const int* col = ei + NE;

    int*   bh    = (int*)d_ws;                       // 100096
    int*   bsum  = bh + SCANN;                       // 128
    int*   boff  = bsum + 128;                       // 128
    float* dis   = (float*)(boff + 128);             // NN
    int*   inc   = (int*)(dis + NN);                 // NN
    int*   ebuck = inc + NN;                         // NE   (offset 1900352, %4==0)
    int2*  esrc8 = (int2*)(ebuck + NE);              // NE int2 (16B-aligned)
    float* h1    = (float*)(esrc8 + NE);             // NN*32
    float* r1    = h1 + (size_t)NN * FH2;            // NN*32
    float* h2    = r1 + (size_t)NN * FH2;            // NN*2
    float* r2    = h2 + (size_t)NN * KS;             // NN*2

    const int B = 256;
    k_hist_dense1<<<NBLK + DENSE_BLOCKS, B, 0, stream>>>(col, bh, x, Wi1, Wr1, b1, h1, r1);
    k_scan1<<<SCAN_BLOCKS, B, 0, stream>>>(bh, bsum);
    k_scan2<<<1, 128, 0, stream>>>(bsum, boff);
    k_scan3<<<(SCANN + B - 1) / B, B, 0, stream>>>(bh, boff);
    k_bscatter<<<NBLK, B, 0, stream>>>(row, col, bh, ebuck);
    k_bcsr_a<<<NB, B, 0, stream>>>(bh, ebuck, inc, dis);
    k_bcsr_b<<<NB, B, 0, stream>>>(bh, ebuck, inc, dis, esrc8);
    k_gather1_mid<<<(NN * 8 + B - 1) / B, B, 0, stream>>>(inc, esrc8,
        (const float4*)h1, (const float4*)r1, (const float4*)Wi2, (const float4*)Wr2,
        b2, h2, r2);
    k_gather2<<<(NN * 8 + B - 1) / B, B, 0, stream>>>(inc, esrc8, h2, r2, out);
}

// Round 8
// 141.338 us; speedup vs baseline: 1.0260x; 1.0260x over previous
//
#include <hip/hip_runtime.h>

#define NN 100000
#define NE 1600000

constexpr int F_IN = 58;
constexpr int F_H  = 16;
constexpr int KS   = 2;
constexpr int FH2  = 32;            // KS * F_H
constexpr int NODES_PER_BLK = 8;
constexpr int SXP = 60;             // padded x-row stride (even, for float2 reads)
constexpr int NPAIR = F_IN / 2;     // 29

constexpr int NB   = 391;           // buckets: col >> 8
constexpr int NBLK = 256;           // partition blocks
constexpr int EPB  = NE / NBLK;     // 6250
constexpr int SCANN = NB * NBLK;    // 100096
constexpr int SCAN_BLOCKS = (SCANN + 1023) / 1024;  // 98
constexpr int DENSE_BLOCKS = (NN + NODES_PER_BLK - 1) / NODES_PER_BLK;

// blocks [0,NBLK): per-block bucket histogram (4-way replicated LDS atomics).
// blocks [NBLK,...): dense layer-1 with paired-b64 LDS reads (2-way = free).
__global__ void k_hist_dense1(const int* __restrict__ col, int* __restrict__ bh,
                              const float* __restrict__ x,
                              const float* __restrict__ Wi, const float* __restrict__ Wr,
                              const float* __restrict__ b,
                              float* __restrict__ h1, float* __restrict__ r1) {
    __shared__ float swi2[NPAIR * 64];   // [pair][ko*2 + q] = Wi[2p+q][ko]
    __shared__ float swr2[NPAIR * 64];
    __shared__ float sx[NODES_PER_BLK * SXP];
    __shared__ int hist[4 * NB];
    int tid = threadIdx.x;

    if (blockIdx.x < NBLK) {
        int blk = blockIdx.x;
        for (int i = tid; i < 4 * NB; i += 256) hist[i] = 0;
        __syncthreads();
        int base = blk * EPB;
        int c0 = (tid & 3) * NB;
        for (int e = base + tid; e < base + EPB; e += 256)
            atomicAdd(&hist[c0 + (col[e] >> 8)], 1);
        __syncthreads();
        for (int i = tid; i < NB; i += 256)
            bh[i * NBLK + blk] = hist[i] + hist[NB + i] + hist[2 * NB + i] + hist[3 * NB + i];
        return;
    }

    // pack weight pairs: swi2[p*64 + ko*2 + q] = Wi[(k*F_IN + 2p+q)*F_H + o]
    for (int t = tid; t < NPAIR * 64; t += 256) {
        int p = t >> 6, r = t & 63;
        int ko = r >> 1, q = r & 1;
        int i = p * 2 + q;
        int k = ko >> 4, o = ko & 15;
        swi2[t] = Wi[(k * F_IN + i) * F_H + o];
        swr2[t] = Wr[(k * F_IN + i) * F_H + o];
    }
    int nodeBase = (blockIdx.x - NBLK) * NODES_PER_BLK;
    for (int t = tid; t < NODES_PER_BLK * F_IN; t += 256) {
        int ln = t / F_IN, i = t - ln * F_IN;
        int n = nodeBase + ln;
        sx[ln * SXP + i] = (n < NN) ? x[n * F_IN + i] : 0.f;
    }
    __syncthreads();
    int ln = tid >> 5, ko = tid & 31;
    int n = nodeBase + ln;
    if (n >= NN) return;
    float hi = 0.f, hr = 0.f;
#pragma unroll
    for (int p = 0; p < NPAIR; p++) {
        float2 xv = *(const float2*)&sx[ln * SXP + p * 2];
        float2 wi = *(const float2*)&swi2[(p << 6) + (ko << 1)];
        float2 wr = *(const float2*)&swr2[(p << 6) + (ko << 1)];
        hi = fmaf(xv.x, wi.x, hi);
        hi = fmaf(xv.y, wi.y, hi);
        hr = fmaf(xv.x, wr.x, hr);
        hr = fmaf(xv.y, wr.y, hr);
    }
    h1[n * FH2 + ko] = hi;
    r1[n * FH2 + ko] = hr + b[ko];
}

__global__ void k_scan1(int* __restrict__ bh, int* __restrict__ bsum) {
    __shared__ int ts[256];
    int tid = threadIdx.x;
    int base = blockIdx.x * 1024 + tid * 4;
    int v0 = (base + 0 < SCANN) ? bh[base + 0] : 0;
    int v1 = (base + 1 < SCANN) ? bh[base + 1] : 0;
    int v2 = (base + 2 < SCANN) ? bh[base + 2] : 0;
    int v3 = (base + 3 < SCANN) ? bh[base + 3] : 0;
    int p0 = v0, p1 = p0 + v1, p2 = p1 + v2, p3 = p2 + v3;
    ts[tid] = p3;
    __syncthreads();
    for (int off = 1; off < 256; off <<= 1) {
        int v = (tid >= off) ? ts[tid - off] : 0;
        __syncthreads();
        ts[tid] += v;
        __syncthreads();
    }
    int prev = (tid > 0) ? ts[tid - 1] : 0;
    if (base + 0 < SCANN) bh[base + 0] = prev + p0;
    if (base + 1 < SCANN) bh[base + 1] = prev + p1;
    if (base + 2 < SCANN) bh[base + 2] = prev + p2;
    if (base + 3 < SCANN) bh[base + 3] = prev + p3;
    if (tid == 255) bsum[blockIdx.x] = ts[255];
}

__global__ void k_scan2(const int* __restrict__ bsum, int* __restrict__ boff) {
    __shared__ int s[128];
    int tid = threadIdx.x;
    s[tid] = (tid < SCAN_BLOCKS) ? bsum[tid] : 0;
    __syncthreads();
    for (int off = 1; off < 128; off <<= 1) {
        int v = (tid >= off) ? s[tid - off] : 0;
        __syncthreads();
        s[tid] += v;
        __syncthreads();
    }
    if (tid < SCAN_BLOCKS) boff[tid] = (tid > 0) ? s[tid - 1] : 0;
}

__global__ void k_scan3(int* __restrict__ bh, const int* __restrict__ boff) {
    int i = blockIdx.x * blockDim.x + threadIdx.x;
    if (i < SCANN) bh[i] += boff[i >> 10];
}

__global__ void k_bscatter(const int* __restrict__ row, const int* __restrict__ col,
                           const int* __restrict__ bh, int* __restrict__ ebuck) {
    __shared__ int cur[NB];
    int tid = threadIdx.x, blk = blockIdx.x;
    for (int i = tid; i < NB; i += 256) {
        int idx = i * NBLK + blk;
        cur[i] = (idx == 0) ? 0 : bh[idx - 1];
    }
    __syncthreads();
    int base = blk * EPB;
    for (int e = base + tid; e < base + EPB; e += 256) {
        int c = col[e];
        int pos = atomicAdd(&cur[c >> 8], 1);
        ebuck[pos] = (row[e] << 8) | (c & 255);
    }
}

// per bucket: per-col counts (2-way replicated) + scan -> inc, dis
__global__ void __launch_bounds__(256) k_bcsr_a(const int* __restrict__ bh,
                                                const int* __restrict__ ebuck,
                                                int* __restrict__ inc, float* __restrict__ dis) {
    __shared__ int cnt[514];
    __shared__ int scn[256];
    int b = blockIdx.x, tid = threadIdx.x;
    int start = (b == 0) ? 0 : bh[b * NBLK - 1];
    int end   = bh[(b + 1) * NBLK - 1];
    cnt[tid] = 0; cnt[257 + tid] = 0;
    __syncthreads();
    int c0 = (tid & 1) * 257;
    for (int j = start + tid; j < end; j += 256)
        atomicAdd(&cnt[c0 + (ebuck[j] & 255)], 1);
    __syncthreads();
    int v = cnt[tid] + cnt[257 + tid];
    scn[tid] = v;
    __syncthreads();
    for (int off = 1; off < 256; off <<= 1) {
        int t = (tid >= off) ? scn[tid - off] : 0;
        __syncthreads();
        scn[tid] += t;
        __syncthreads();
    }
    int colIdx = (b << 8) + tid;
    if (colIdx < NN) {
        inc[colIdx] = start + scn[tid];
        dis[colIdx] = (v > 0) ? rsqrtf((float)v) : 0.f;
    }
}

// per bucket: scatter packed (src, w = dis[src]*dis[col]) into CSR order
__global__ void __launch_bounds__(256) k_bcsr_b(const int* __restrict__ bh,
                                                const int* __restrict__ ebuck,
                                                const int* __restrict__ inc,
                                                const float* __restrict__ dis,
                                                int2* __restrict__ esrc8) {
    __shared__ int cur[256];
    __shared__ float sdis[256];
    int b = blockIdx.x, tid = threadIdx.x;
    int start = (b == 0) ? 0 : bh[b * NBLK - 1];
    int end   = bh[(b + 1) * NBLK - 1];
    int colIdx = (b << 8) + tid;
    cur[tid]  = (colIdx == 0) ? 0 : ((colIdx <= NN) ? inc[colIdx - 1] : 0);
    sdis[tid] = (colIdx < NN) ? dis[colIdx] : 0.f;
    __syncthreads();
    for (int j = start + tid; j < end; j += 256) {
        int e = ebuck[j];
        int c = e & 255, s = e >> 8;
        int pos = atomicAdd(&cur[c], 1);
        float w = dis[s] * sdis[c];
        esrc8[pos] = make_int2(s, __float_as_int(w));
    }
}

// layer1 gather + relu + K-mean + dense2. 8 lanes/node, float4 rows, packed edges.
__global__ void k_gather1_mid(const int* __restrict__ inc, const int2* __restrict__ esrc8,
                              const float4* __restrict__ h1, const float4* __restrict__ r1,
                              const float4* __restrict__ Wi2, const float4* __restrict__ Wr2,
                              const float* __restrict__ b2,
                              float* __restrict__ h2, float* __restrict__ r2) {
    int tid = blockIdx.x * blockDim.x + threadIdx.x;
    int n = tid >> 3, l = tid & 7;
    if (n >= NN) return;
    int js = (n == 0) ? 0 : inc[n - 1];
    int je = inc[n];
    float4 acc = r1[(size_t)n * 8 + l];
    int j = js;
    if ((j & 1) && j < je) {
        int2 e = esrc8[j];
        float w = __int_as_float(e.y);
        float4 v = h1[(size_t)e.x * 8 + l];
        acc.x = fmaf(w, v.x, acc.x); acc.y = fmaf(w, v.y, acc.y);
        acc.z = fmaf(w, v.z, acc.z); acc.w = fmaf(w, v.w, acc.w);
        j++;
    }
    for (; j + 1 < je; j += 2) {
        int4 ep = *(const int4*)&esrc8[j];
        float w0 = __int_as_float(ep.y), w1 = __int_as_float(ep.w);
        float4 v0 = h1[(size_t)ep.x * 8 + l];
        float4 v1 = h1[(size_t)ep.z * 8 + l];
        acc.x = fmaf(w0, v0.x, acc.x); acc.y = fmaf(w0, v0.y, acc.y);
        acc.z = fmaf(w0, v0.z, acc.z); acc.w = fmaf(w0, v0.w, acc.w);
        acc.x = fmaf(w1, v1.x, acc.x); acc.y = fmaf(w1, v1.y, acc.y);
        acc.z = fmaf(w1, v1.z, acc.z); acc.w = fmaf(w1, v1.w, acc.w);
    }
    if (j < je) {
        int2 e = esrc8[j];
        float w = __int_as_float(e.y);
        float4 v = h1[(size_t)e.x * 8 + l];
        acc.x = fmaf(w, v.x, acc.x); acc.y = fmaf(w, v.y, acc.y);
        acc.z = fmaf(w, v.z, acc.z); acc.w = fmaf(w, v.w, acc.w);
    }
    acc.x = fmaxf(acc.x, 0.f); acc.y = fmaxf(acc.y, 0.f);
    acc.z = fmaxf(acc.z, 0.f); acc.w = fmaxf(acc.w, 0.f);
    float4 h;
    h.x = 0.5f * (acc.x + __shfl_xor(acc.x, 4));
    h.y = 0.5f * (acc.y + __shfl_xor(acc.y, 4));
    h.z = 0.5f * (acc.z + __shfl_xor(acc.z, 4));
    h.w = 0.5f * (acc.w + __shfl_xor(acc.w, 4));
    float4 wi = Wi2[l], wr = Wr2[l];
    float p1 = h.x * wi.x + h.y * wi.y + h.z * wi.z + h.w * wi.w;
    float p2 = h.x * wr.x + h.y * wr.y + h.z * wr.z + h.w * wr.w;
    p1 += __shfl_xor(p1, 1); p1 += __shfl_xor(p1, 2);
    p2 += __shfl_xor(p2, 1); p2 += __shfl_xor(p2, 2);
    if ((l & 3) == 0) {
        int k = l >> 2;
        h2[n * 2 + k] = p1;
        r2[n * 2 + k] = p2 + b2[k];
    }
}

// layer2 gather: 8 lanes/node, edge-parallel over packed pairs
__global__ void k_gather2(const int* __restrict__ inc, const int2* __restrict__ esrc8,
                          const float* __restrict__ h2, const float* __restrict__ r2,
                          float* __restrict__ out) {
    int tid = blockIdx.x * blockDim.x + threadIdx.x;
    int n = tid >> 3, l = tid & 7;
    if (n >= NN) return;
    int js = (n == 0) ? 0 : inc[n - 1];
    int je = inc[n];
    float a0 = 0.f, a1v = 0.f;
    for (int j = js + l; j < je; j += 8) {
        int2 e = esrc8[j];
        float w = __int_as_float(e.y);
        float2 hv = *(const float2*)&h2[(size_t)e.x * 2];
        a0  = fmaf(w, hv.x, a0);
        a1v = fmaf(w, hv.y, a1v);
    }
    a0  += __shfl_xor(a0, 1);  a0  += __shfl_xor(a0, 2);  a0  += __shfl_xor(a0, 4);
    a1v += __shfl_xor(a1v, 1); a1v += __shfl_xor(a1v, 2); a1v += __shfl_xor(a1v, 4);
    if (l == 0) {
        float2 rv = *(const float2*)&r2[(size_t)n * 2];
        out[n] = 0.5f * (fmaxf(a0 + rv.x, 0.f) + fmaxf(a1v + rv.y, 0.f));
    }
}

extern "C" void kernel_launch(void* const* d_in, const int* in_sizes, int n_in,
                              void* d_out, int out_size, void* d_ws, size_t ws_size,
                              hipStream_t stream) {
    const float* x   = (const float*)d_in[0];
    const int*   ei  = (const int*)d_in[1];
    const float* Wi1 = (const float*)d_in[2];
    const float* Wr1 = (const float*)d_in[3];
    const float* b1  = (const float*)d_in[4];
    const float* Wi2 = (const float*)d_in[5];
    const float* Wr2 = (const float*)d_in[6];
    const float* b2  = (const float*)d_in[7];
    float* out = (float*)d_out;

    const int* row = ei;
    const int* col = ei + NE;

    int*   bh    = (int*)d_ws;                       // 100096
    int*   bsum  = bh + SCANN;                       // 128
    int*   boff  = bsum + 128;                       // 128
    float* dis   = (float*)(boff + 128);             // NN
    int*   inc   = (int*)(dis + NN);                 // NN
    int*   ebuck = inc + NN;                         // NE
    int2*  esrc8 = (int2*)(ebuck + NE);              // NE int2 (16B-aligned)
    float* h1    = (float*)(esrc8 + NE);             // NN*32
    float* r1    = h1 + (size_t)NN * FH2;            // NN*32
    float* h2    = r1 + (size_t)NN * FH2;            // NN*2
    float* r2    = h2 + (size_t)NN * KS;             // NN*2

    const int B = 256;
    k_hist_dense1<<<NBLK + DENSE_BLOCKS, B, 0, stream>>>(col, bh, x, Wi1, Wr1, b1, h1, r1);
    k_scan1<<<SCAN_BLOCKS, B, 0, stream>>>(bh, bsum);
    k_scan2<<<1, 128, 0, stream>>>(bsum, boff);
    k_scan3<<<(SCANN + B - 1) / B, B, 0, stream>>>(bh, boff);
    k_bscatter<<<NBLK, B, 0, stream>>>(row, col, bh, ebuck);
    k_bcsr_a<<<NB, B, 0, stream>>>(bh, ebuck, inc, dis);
    k_bcsr_b<<<NB, B, 0, stream>>>(bh, ebuck, inc, dis, esrc8);
    k_gather1_mid<<<(NN * 8 + B - 1) / B, B, 0, stream>>>(inc, esrc8,
        (const float4*)h1, (const float4*)r1, (const float4*)Wi2, (const float4*)Wr2,
        b2, h2, r2);
    k_gather2<<<(NN * 8 + B - 1) / B, B, 0, stream>>>(inc, esrc8, h2, r2, out);
}